// Round 1
// baseline (6133.476 us; speedup 1.0000x reference)
//
#include <hip/hip_runtime.h>
#include <math.h>

// Problem dims
#define Sn 128
#define Bn 16
#define Hn 1024
#define En 512
#define Vn 32000
#define H3 3072

typedef __attribute__((ext_vector_type(8))) short bf16x8;   // 8 bf16 in 4 VGPRs
typedef __attribute__((ext_vector_type(4))) float f32x4;

__device__ __forceinline__ unsigned short f2bf(float f) {
  unsigned u = __float_as_uint(f);
  u += 0x7fffu + ((u >> 16) & 1u);          // RNE
  return (unsigned short)(u >> 16);
}

// ---------- f32 -> bf16 convert (n multiple of 4) ----------
__global__ void cvt_bf16_k(const float* __restrict__ src, unsigned short* __restrict__ dst, int n4) {
  int i = blockIdx.x * blockDim.x + threadIdx.x;
  if (i < n4) {
    float4 v = *(const float4*)(src + (size_t)i * 4);
    unsigned short* d = dst + (size_t)i * 4;
    d[0] = f2bf(v.x); d[1] = f2bf(v.y); d[2] = f2bf(v.z); d[3] = f2bf(v.w);
  }
}

// ---------- embedding gather -> bf16 X, time-major rows t = s*Bn + b ----------
__global__ void embed_k(const int* __restrict__ trg, const float* __restrict__ emb,
                        unsigned short* __restrict__ Xb) {
  int t = blockIdx.x;                 // 0..2047
  int s = t >> 4, b = t & 15;
  int tok = trg[b * Sn + s];          // trg is (B,S)
  const float* src = emb + (size_t)tok * En;
  int e = threadIdx.x * 4;            // blockDim.x = 128 -> covers 512
  float4 v = *(const float4*)(src + e);
  unsigned short* d = Xb + (size_t)t * En + e;
  d[0] = f2bf(v.x); d[1] = f2bf(v.y); d[2] = f2bf(v.z); d[3] = f2bf(v.w);
}

// ---------- bf16 MFMA GEMM: C(M,N) = A(M,K) @ B(N,K)^T + bias ----------
// OUT_MODE: 0 = f32 row-major, 1 = bf16 row-major, 2 = f32 with row remap t=(s*16+b) -> (b*128+s)
// 128x128 tile, BK=64, 4 waves (2x2), XOR-swizzled LDS (slot ^= row&7) for conflict-free ds_read_b128.
template<int OUT_MODE, bool RELU>
__global__ __launch_bounds__(256) void gemm_bt(
    const unsigned short* __restrict__ A, const unsigned short* __restrict__ B,
    const float* __restrict__ bias, void* __restrict__ C,
    int M, int N, int K)
{
  __shared__ unsigned short As[128 * 64];
  __shared__ unsigned short Bs[128 * 64];
  int tid = threadIdx.x;
  int l = tid & 63, wv = tid >> 6;
  int wr = wv >> 1, wc = wv & 1;
  int brow = blockIdx.y * 128, bcol = blockIdx.x * 128;

  f32x4 acc[4][4];
#pragma unroll
  for (int m = 0; m < 4; ++m)
#pragma unroll
    for (int n = 0; n < 4; ++n) acc[m][n] = (f32x4){0.f, 0.f, 0.f, 0.f};

  int nkt = K >> 6;
  for (int kt = 0; kt < nkt; ++kt) {
    const unsigned short* Ag = A + (size_t)brow * K + kt * 64;
    const unsigned short* Bg = B + (size_t)bcol * K + kt * 64;
#pragma unroll
    for (int c = tid; c < 2048; c += 256) {
      int half = c >> 10;
      int cc = c & 1023;
      int row = cc >> 3, slot = cc & 7;
      const unsigned short* src = (half ? Bg : Ag) + (size_t)row * K + slot * 8;
      uint4 v = *(const uint4*)src;
      unsigned short* dst = (half ? Bs : As) + row * 64 + ((slot ^ (row & 7)) << 3);
      *(uint4*)dst = v;
    }
    __syncthreads();
#pragma unroll
    for (int kk = 0; kk < 2; ++kk) {
      bf16x8 af[4], bfr[4];
      int rb = wr * 64 + (l & 15);
      int cb2 = wc * 64 + (l & 15);
      int slot = kk * 4 + (l >> 4);
#pragma unroll
      for (int m = 0; m < 4; ++m) {
        int r = rb + m * 16;
        af[m] = *(const bf16x8*)&As[r * 64 + ((slot ^ (r & 7)) << 3)];
      }
#pragma unroll
      for (int n = 0; n < 4; ++n) {
        int r = cb2 + n * 16;
        bfr[n] = *(const bf16x8*)&Bs[r * 64 + ((slot ^ (r & 7)) << 3)];
      }
#pragma unroll
      for (int m = 0; m < 4; ++m)
#pragma unroll
        for (int n = 0; n < 4; ++n)
          acc[m][n] = __builtin_amdgcn_mfma_f32_16x16x32_bf16(af[m], bfr[n], acc[m][n], 0, 0, 0);
    }
    __syncthreads();
  }

  // epilogue: D frag layout col = lane&15, row = 4*(lane>>4)+i  (m89-verified)
#pragma unroll
  for (int m = 0; m < 4; ++m) {
    int row0 = brow + wr * 64 + m * 16 + ((l >> 4) << 2);
#pragma unroll
    for (int n = 0; n < 4; ++n) {
      int col = bcol + wc * 64 + n * 16 + (l & 15);
      float bv = bias ? bias[col] : 0.f;
#pragma unroll
      for (int i = 0; i < 4; ++i) {
        int row = row0 + i;
        float v = acc[m][n][i] + bv;
        if (RELU) v = fmaxf(v, 0.f);
        if (OUT_MODE == 1) {
          ((unsigned short*)C)[(size_t)row * N + col] = f2bf(v);
        } else if (OUT_MODE == 2) {
          int rr = ((row & 15) << 7) + (row >> 4);   // (b*128 + s)
          ((float*)C)[(size_t)rr * N + col] = v;
        } else {
          ((float*)C)[(size_t)row * N + col] = v;
        }
      }
    }
  }
}

// ---------- pipelined GRU step: blocks [0,256) do layer0[s], [256,512) do layer1[s-1] ----------
// fp32 throughout (recurrence accuracy). Each wave owns one output column j; lanes split
// 16 rows x 4 k-phases. h staged in padded LDS (PW=1032 words) for float4 reads.
__global__ __launch_bounds__(256) void gru_pipe(
    int s,
    const float* __restrict__ gi0_all,
    const float* __restrict__ h0_prev, float* __restrict__ h0_out,
    const float* __restrict__ h1_prev, float* __restrict__ h1_out,
    const float* __restrict__ h0_l1,
    const float* __restrict__ w_hh0, const float* __restrict__ b_hh0,
    const float* __restrict__ w_ih1, const float* __restrict__ b_ih1,
    const float* __restrict__ w_hh1, const float* __restrict__ b_hh1,
    unsigned short* __restrict__ h1bf)
{
  extern __shared__ float lds[];
  const int PW = 1032;
  int layer = blockIdx.x >> 8;
  int cb = blockIdx.x & 255;
  int tid = threadIdx.x;
  int l = tid & 63, wv = tid >> 6;
  int j = cb * 4 + wv;
  int b = l >> 2, p = l & 3;

  if (layer == 0) {
    if (s >= Sn) return;
    float* hs = lds;
    for (int i = tid; i < 4096; i += 256) {
      int row = i >> 8, col = (i & 255) << 2;
      *(float4*)(hs + row * PW + col) = *(const float4*)(h0_prev + row * Hn + col);
    }
    __syncthreads();
    const float* wrp = w_hh0 + (size_t)j * Hn;
    const float* wzp = w_hh0 + (size_t)(Hn + j) * Hn;
    const float* wnp = w_hh0 + (size_t)(2 * Hn + j) * Hn;
    float ar = 0.f, az = 0.f, an = 0.f;
    for (int k = 4 * p; k < Hn; k += 16) {
      float4 h4 = *(const float4*)(hs + b * PW + k);
      float4 r4 = *(const float4*)(wrp + k);
      float4 z4 = *(const float4*)(wzp + k);
      float4 n4 = *(const float4*)(wnp + k);
      ar = fmaf(h4.x, r4.x, fmaf(h4.y, r4.y, fmaf(h4.z, r4.z, fmaf(h4.w, r4.w, ar))));
      az = fmaf(h4.x, z4.x, fmaf(h4.y, z4.y, fmaf(h4.z, z4.z, fmaf(h4.w, z4.w, az))));
      an = fmaf(h4.x, n4.x, fmaf(h4.y, n4.y, fmaf(h4.z, n4.z, fmaf(h4.w, n4.w, an))));
    }
    ar += __shfl_xor(ar, 1, 64); ar += __shfl_xor(ar, 2, 64);
    az += __shfl_xor(az, 1, 64); az += __shfl_xor(az, 2, 64);
    an += __shfl_xor(an, 1, 64); an += __shfl_xor(an, 2, 64);
    if (p == 0) {
      const float* gi = gi0_all + (size_t)(s * Bn + b) * H3;
      float ir = gi[j], iz = gi[Hn + j], inn = gi[2 * Hn + j];
      float hr = ar + b_hh0[j];
      float hz = az + b_hh0[Hn + j];
      float hn = an + b_hh0[2 * Hn + j];
      float r = 1.f / (1.f + expf(-(ir + hr)));
      float z = 1.f / (1.f + expf(-(iz + hz)));
      float n = tanhf(inn + r * hn);
      float hp = hs[b * PW + j];
      h0_out[b * Hn + j] = (1.f - z) * n + z * hp;
    }
  } else {
    if (s == 0) return;
    float* hs = lds;
    float* xs = lds + 16 * PW;
    for (int i = tid; i < 4096; i += 256) {
      int row = i >> 8, col = (i & 255) << 2;
      *(float4*)(hs + row * PW + col) = *(const float4*)(h1_prev + row * Hn + col);
      *(float4*)(xs + row * PW + col) = *(const float4*)(h0_l1 + row * Hn + col);
    }
    __syncthreads();
    const float* uir = w_ih1 + (size_t)j * Hn;
    const float* uiz = w_ih1 + (size_t)(Hn + j) * Hn;
    const float* uin = w_ih1 + (size_t)(2 * Hn + j) * Hn;
    const float* whr = w_hh1 + (size_t)j * Hn;
    const float* whz = w_hh1 + (size_t)(Hn + j) * Hn;
    const float* whn = w_hh1 + (size_t)(2 * Hn + j) * Hn;
    float air = 0.f, aiz = 0.f, ain = 0.f, ahr = 0.f, ahz = 0.f, ahn = 0.f;
    for (int k = 4 * p; k < Hn; k += 16) {
      float4 x4 = *(const float4*)(xs + b * PW + k);
      float4 h4 = *(const float4*)(hs + b * PW + k);
      float4 a4 = *(const float4*)(uir + k);
      float4 c4 = *(const float4*)(uiz + k);
      float4 d4 = *(const float4*)(uin + k);
      float4 e4 = *(const float4*)(whr + k);
      float4 f4 = *(const float4*)(whz + k);
      float4 g4 = *(const float4*)(whn + k);
      air = fmaf(x4.x, a4.x, fmaf(x4.y, a4.y, fmaf(x4.z, a4.z, fmaf(x4.w, a4.w, air))));
      aiz = fmaf(x4.x, c4.x, fmaf(x4.y, c4.y, fmaf(x4.z, c4.z, fmaf(x4.w, c4.w, aiz))));
      ain = fmaf(x4.x, d4.x, fmaf(x4.y, d4.y, fmaf(x4.z, d4.z, fmaf(x4.w, d4.w, ain))));
      ahr = fmaf(h4.x, e4.x, fmaf(h4.y, e4.y, fmaf(h4.z, e4.z, fmaf(h4.w, e4.w, ahr))));
      ahz = fmaf(h4.x, f4.x, fmaf(h4.y, f4.y, fmaf(h4.z, f4.z, fmaf(h4.w, f4.w, ahz))));
      ahn = fmaf(h4.x, g4.x, fmaf(h4.y, g4.y, fmaf(h4.z, g4.z, fmaf(h4.w, g4.w, ahn))));
    }
    air += __shfl_xor(air, 1, 64); air += __shfl_xor(air, 2, 64);
    aiz += __shfl_xor(aiz, 1, 64); aiz += __shfl_xor(aiz, 2, 64);
    ain += __shfl_xor(ain, 1, 64); ain += __shfl_xor(ain, 2, 64);
    ahr += __shfl_xor(ahr, 1, 64); ahr += __shfl_xor(ahr, 2, 64);
    ahz += __shfl_xor(ahz, 1, 64); ahz += __shfl_xor(ahz, 2, 64);
    ahn += __shfl_xor(ahn, 1, 64); ahn += __shfl_xor(ahn, 2, 64);
    if (p == 0) {
      float ir = air + b_ih1[j], iz = aiz + b_ih1[Hn + j], inn = ain + b_ih1[2 * Hn + j];
      float hr = ahr + b_hh1[j], hz = ahz + b_hh1[Hn + j], hn = ahn + b_hh1[2 * Hn + j];
      float r = 1.f / (1.f + expf(-(ir + hr)));
      float z = 1.f / (1.f + expf(-(iz + hz)));
      float n = tanhf(inn + r * hn);
      float hp = hs[b * PW + j];
      float out = (1.f - z) * n + z * hp;
      h1_out[b * Hn + j] = out;
      h1bf[b * Hn + j] = f2bf(out);
    }
  }
}

extern "C" void kernel_launch(void* const* d_in, const int* in_sizes, int n_in,
                              void* d_out, int out_size, void* d_ws, size_t ws_size,
                              hipStream_t stream) {
  const float* hidden = (const float*)d_in[0];
  const int*   trg    = (const int*)d_in[1];
  const float* emb    = (const float*)d_in[2];
  const float* w_ih0  = (const float*)d_in[3];
  const float* w_hh0  = (const float*)d_in[4];
  const float* b_ih0  = (const float*)d_in[5];
  const float* b_hh0  = (const float*)d_in[6];
  const float* w_ih1  = (const float*)d_in[7];
  const float* w_hh1  = (const float*)d_in[8];
  const float* b_ih1  = (const float*)d_in[9];
  const float* b_hh1  = (const float*)d_in[10];
  const float* w1     = (const float*)d_in[11];
  const float* b1     = (const float*)d_in[12];
  const float* w2     = (const float*)d_in[13];
  const float* b2     = (const float*)d_in[14];
  const float* b_gen  = (const float*)d_in[15];

  // workspace layout (~77.1 MB total)
  char* ws = (char*)d_ws;
  size_t off = 0;
  float* GI0            = (float*)(ws + off);          off += (size_t)Sn * Bn * H3 * 4;
  unsigned short* Xb    = (unsigned short*)(ws + off); off += (size_t)Sn * Bn * En * 2;
  unsigned short* embB  = (unsigned short*)(ws + off); off += (size_t)Vn * En * 2;
  unsigned short* wih0B = (unsigned short*)(ws + off); off += (size_t)H3 * En * 2;
  unsigned short* w1B   = (unsigned short*)(ws + off); off += (size_t)Hn * Hn * 2;
  unsigned short* w2B   = (unsigned short*)(ws + off); off += (size_t)En * Hn * 2;
  unsigned short* H1A   = (unsigned short*)(ws + off); off += (size_t)Sn * Bn * Hn * 2;
  unsigned short* Tb    = (unsigned short*)(ws + off); off += (size_t)Sn * Bn * Hn * 2;
  unsigned short* Ub    = (unsigned short*)(ws + off); off += (size_t)Sn * Bn * En * 2;
  float* h0pp[2]; float* h1pp[2];
  h0pp[0] = (float*)(ws + off); off += (size_t)Bn * Hn * 4;
  h0pp[1] = (float*)(ws + off); off += (size_t)Bn * Hn * 4;
  h1pp[0] = (float*)(ws + off); off += (size_t)Bn * Hn * 4;
  h1pp[1] = (float*)(ws + off); off += (size_t)Bn * Hn * 4;

  // bf16 copies of the batch-GEMM operands
  cvt_bf16_k<<<16000, 256, 0, stream>>>(emb,   embB,  Vn * En / 4);
  cvt_bf16_k<<<1536,  256, 0, stream>>>(w_ih0, wih0B, H3 * En / 4);
  cvt_bf16_k<<<1024,  256, 0, stream>>>(w1,    w1B,   Hn * Hn / 4);
  cvt_bf16_k<<<512,   256, 0, stream>>>(w2,    w2B,   En * Hn / 4);
  embed_k<<<Sn * Bn, 128, 0, stream>>>(trg, emb, Xb);

  // GI0 = X @ w_ih0^T + b_ih0 for all (s,b) rows (hoisted out of the recurrence)
  gemm_bt<0, false><<<dim3(H3 / 128, (Sn * Bn) / 128), 256, 0, stream>>>(
      Xb, wih0B, b_ih0, GI0, Sn * Bn, H3, En);

  // sequential recurrence, layer0[s] pipelined with layer1[s-1]: 129 launches
  const int LDSZ = 2 * 16 * 1032 * 4;   // 132096 B
  hipFuncSetAttribute(reinterpret_cast<const void*>(gru_pipe),
                      hipFuncAttributeMaxDynamicSharedMemorySize, LDSZ);
  for (int s = 0; s <= Sn; ++s) {
    const float* h0p  = (s == 0) ? hidden : h0pp[(s + 1) & 1];
    float*       h0o  = h0pp[s & 1];
    const float* h0l1 = (s == 0) ? hidden : h0pp[(s + 1) & 1];   // h0[s-1]
    const float* h1p  = (s == 1) ? (hidden + Bn * Hn) : h1pp[s & 1];
    float*       h1o  = h1pp[(s + 1) & 1];
    unsigned short* h1b = H1A + (size_t)((s >= 1) ? (s - 1) : 0) * Bn * Hn;
    gru_pipe<<<512, 256, LDSZ, stream>>>(s, GI0, h0p, h0o, h1p, h1o, h0l1,
                                         w_hh0, b_hh0, w_ih1, b_ih1, w_hh1, b_hh1, h1b);
  }

  // output head, batched over all 2048 rows
  gemm_bt<1, true ><<<dim3(Hn / 128, (Sn * Bn) / 128), 256, 0, stream>>>(
      H1A, w1B, b1, Tb, Sn * Bn, Hn, Hn);
  gemm_bt<1, false><<<dim3(En / 128, (Sn * Bn) / 128), 256, 0, stream>>>(
      Tb, w2B, b2, Ub, Sn * Bn, En, Hn);
  gemm_bt<2, false><<<dim3(Vn / 128, (Sn * Bn) / 128), 256, 0, stream>>>(
      Ub, embB, b_gen, (float*)d_out, Sn * Bn, Vn, En);
}

// Round 2
// 3191.682 us; speedup vs baseline: 1.9217x; 1.9217x over previous
//
#include <hip/hip_runtime.h>
#include <math.h>

// Problem dims
#define Sn 128
#define Bn 16
#define Hn 1024
#define En 512
#define Vn 32000
#define H3 3072

typedef _Float16 h16;
typedef __attribute__((ext_vector_type(4))) _Float16 h16x4;
typedef __attribute__((ext_vector_type(8))) _Float16 h16x8;
typedef __attribute__((ext_vector_type(4))) float f32x4;

// ---------- f32 -> fp16 convert (n4 = count of float4 quads) ----------
__global__ void cvt_f16_k(const float* __restrict__ src, h16* __restrict__ dst, int n4) {
  int i = blockIdx.x * blockDim.x + threadIdx.x;
  if (i < n4) {
    float4 v = *(const float4*)(src + (size_t)i * 4);
    h16x4 o = { (h16)v.x, (h16)v.y, (h16)v.z, (h16)v.w };
    *(h16x4*)(dst + (size_t)i * 4) = o;
  }
}

// ---------- embedding gather -> fp16 X, time-major rows t = s*Bn + b ----------
__global__ void embed_k(const int* __restrict__ trg, const float* __restrict__ emb,
                        h16* __restrict__ Xh) {
  int t = blockIdx.x;                 // 0..2047
  int s = t >> 4, b = t & 15;
  int tok = trg[b * Sn + s];          // trg is (B,S)
  const float* src = emb + (size_t)tok * En;
  int e = threadIdx.x * 4;            // blockDim.x = 128 -> covers 512
  float4 v = *(const float4*)(src + e);
  h16x4 o = { (h16)v.x, (h16)v.y, (h16)v.z, (h16)v.w };
  *(h16x4*)(Xh + (size_t)t * En + e) = o;
}

// ---------- fp16 MFMA GEMM: C(M,N) = A(M,K) @ B(N,K)^T + bias ----------
// OUT_MODE: 0 = f32 row-major, 1 = fp16 row-major, 2 = f32 with row remap (s*16+b) -> (b*128+s)
// 1D grid, M-panel-fastest; SWZ = bijective XCD swizzle (gridDim.x % 8 == 0 required)
// 128x128 tile, BK=64, 4 waves (2x2), XOR-swizzled LDS for conflict-free ds_read_b128.
template<int OUT_MODE, bool RELU, bool SWZ>
__global__ __launch_bounds__(256) void gemm_bt(
    const h16* __restrict__ A, const h16* __restrict__ B,
    const float* __restrict__ bias, void* __restrict__ C,
    int M, int N, int K)
{
  __shared__ h16 As[128 * 64];
  __shared__ h16 Bs[128 * 64];
  int tid = threadIdx.x;
  int l = tid & 63, wv = tid >> 6;
  int wr = wv >> 1, wc = wv & 1;

  int work = blockIdx.x;
  if (SWZ) { int q = gridDim.x >> 3; work = (work & 7) * q + (work >> 3); }
  int nMp = M >> 7;
  int brow = (work % nMp) << 7;
  int bcol = (work / nMp) << 7;

  f32x4 acc[4][4];
#pragma unroll
  for (int m = 0; m < 4; ++m)
#pragma unroll
    for (int n = 0; n < 4; ++n) acc[m][n] = (f32x4){0.f, 0.f, 0.f, 0.f};

  int nkt = K >> 6;
  for (int kt = 0; kt < nkt; ++kt) {
    const h16* Ag = A + (size_t)brow * K + kt * 64;
    const h16* Bg = B + (size_t)bcol * K + kt * 64;
#pragma unroll
    for (int c = tid; c < 2048; c += 256) {
      int half = c >> 10;
      int cc = c & 1023;
      int row = cc >> 3, slot = cc & 7;
      const h16* src = (half ? Bg : Ag) + (size_t)row * K + slot * 8;
      uint4 v = *(const uint4*)src;
      h16* dst = (half ? Bs : As) + row * 64 + ((slot ^ (row & 7)) << 3);
      *(uint4*)dst = v;
    }
    __syncthreads();
#pragma unroll
    for (int kk = 0; kk < 2; ++kk) {
      h16x8 af[4], bfr[4];
      int rb = wr * 64 + (l & 15);
      int cb2 = wc * 64 + (l & 15);
      int slot = kk * 4 + (l >> 4);
#pragma unroll
      for (int m = 0; m < 4; ++m) {
        int r = rb + m * 16;
        af[m] = *(const h16x8*)&As[r * 64 + ((slot ^ (r & 7)) << 3)];
      }
#pragma unroll
      for (int n = 0; n < 4; ++n) {
        int r = cb2 + n * 16;
        bfr[n] = *(const h16x8*)&Bs[r * 64 + ((slot ^ (r & 7)) << 3)];
      }
#pragma unroll
      for (int m = 0; m < 4; ++m)
#pragma unroll
        for (int n = 0; n < 4; ++n)
          acc[m][n] = __builtin_amdgcn_mfma_f32_16x16x32_f16(af[m], bfr[n], acc[m][n], 0, 0, 0);
    }
    __syncthreads();
  }

  // epilogue: D frag layout col = lane&15, row = 4*(lane>>4)+i
#pragma unroll
  for (int m = 0; m < 4; ++m) {
    int row0 = brow + wr * 64 + m * 16 + ((l >> 4) << 2);
#pragma unroll
    for (int n = 0; n < 4; ++n) {
      int col = bcol + wc * 64 + n * 16 + (l & 15);
      float bv = bias ? bias[col] : 0.f;
#pragma unroll
      for (int i = 0; i < 4; ++i) {
        int row = row0 + i;
        float v = acc[m][n][i] + bv;
        if (RELU) v = fmaxf(v, 0.f);
        if (OUT_MODE == 1) {
          ((h16*)C)[(size_t)row * N + col] = (h16)v;
        } else if (OUT_MODE == 2) {
          int rr = ((row & 15) << 7) + (row >> 4);   // (b*128 + s)
          ((float*)C)[(size_t)rr * N + col] = v;
        } else {
          ((float*)C)[(size_t)row * N + col] = v;
        }
      }
    }
  }
}

// ---------- pipelined GRU step ----------
// Blocks [0,256): layer0[s]; [256,512): layer1[s-1].
// fp16 weights + fp16 staged h/x for the dot products (v_fma_mix),
// fp32 running state for the (1-z)*n + z*h update (read directly from global).
// LDS: layer0 = 16x1024 fp16 (padded rows of 1032); layer1 = 2 such buffers = 64.5KB
// -> 2 blocks/CU (one layer0 + one layer1), 8 waves/CU.
__global__ __launch_bounds__(256) void gru_step(
    int s,
    const float* __restrict__ gi0_all,
    const float* __restrict__ h0p32, float* __restrict__ h0o32,
    const h16* __restrict__ h0p16, h16* __restrict__ h0o16,
    const float* __restrict__ h1p32, float* __restrict__ h1o32,
    const h16* __restrict__ h1p16, h16* __restrict__ h1o16,
    const h16* __restrict__ whh0, const float* __restrict__ bhh0,
    const h16* __restrict__ wih1, const float* __restrict__ bih1,
    const h16* __restrict__ whh1, const float* __restrict__ bhh1)
{
  extern __shared__ char smem[];
  h16* lds0 = (h16*)smem;
  const int PW = 1032;                 // padded row (h16 units): 2064B, 16B-aligned
  int tid = threadIdx.x;
  int l = tid & 63, wv = tid >> 6;
  int b = l >> 2, p = l & 3;

  if (blockIdx.x < 256) {
    // ---------------- layer 0, step s ----------------
    if (s >= Sn) return;
    int j = blockIdx.x * 4 + wv;       // 0..1023
#pragma unroll
    for (int it = 0; it < 8; ++it) {
      int e = it * 2048 + tid * 8;
      int row = e >> 10, col = e & 1023;
      *(uint4*)(lds0 + row * PW + col) = *(const uint4*)(h0p16 + e);
    }
    __syncthreads();
    const h16* wr = whh0 + (size_t)j * Hn;
    const h16* wz = wr + (size_t)Hn * Hn;
    const h16* wn = wz + (size_t)Hn * Hn;
    const h16* hb = lds0 + b * PW;
    float ar = 0.f, az = 0.f, an = 0.f;
#pragma unroll 4
    for (int t = 0; t < 64; ++t) {
      int k = 4 * p + 16 * t;
      h16x4 h4 = *(const h16x4*)(hb + k);
      h16x4 r4 = *(const h16x4*)(wr + k);
      h16x4 z4 = *(const h16x4*)(wz + k);
      h16x4 n4 = *(const h16x4*)(wn + k);
#pragma unroll
      for (int q = 0; q < 4; ++q) {
        float hf = (float)h4[q];
        ar = fmaf(hf, (float)r4[q], ar);
        az = fmaf(hf, (float)z4[q], az);
        an = fmaf(hf, (float)n4[q], an);
      }
    }
    ar += __shfl_xor(ar, 1, 64); ar += __shfl_xor(ar, 2, 64);
    az += __shfl_xor(az, 1, 64); az += __shfl_xor(az, 2, 64);
    an += __shfl_xor(an, 1, 64); an += __shfl_xor(an, 2, 64);
    if (p == 0) {
      const float* gi = gi0_all + (size_t)(s * Bn + b) * H3;
      float ir = gi[j], iz = gi[Hn + j], inn = gi[2 * Hn + j];
      float hr = ar + bhh0[j];
      float hz = az + bhh0[Hn + j];
      float hn = an + bhh0[2 * Hn + j];
      float r = 1.f / (1.f + expf(-(ir + hr)));
      float z = 1.f / (1.f + expf(-(iz + hz)));
      float n = tanhf(inn + r * hn);
      float hp = h0p32[b * Hn + j];
      float out = (1.f - z) * n + z * hp;
      h0o32[b * Hn + j] = out;
      h0o16[b * Hn + j] = (h16)out;
    }
  } else {
    // ---------------- layer 1, step s-1 ----------------
    if (s == 0) return;
    int j = (blockIdx.x - 256) * 4 + wv;
    h16* xs = lds0;
    h16* hs = lds0 + 16 * PW;
#pragma unroll
    for (int it = 0; it < 8; ++it) {
      int e = it * 2048 + tid * 8;
      int row = e >> 10, col = e & 1023;
      *(uint4*)(xs + row * PW + col) = *(const uint4*)(h0p16 + e);   // x = h0[s-1] fp16
      *(uint4*)(hs + row * PW + col) = *(const uint4*)(h1p16 + e);   // h1[s-2] fp16
    }
    __syncthreads();
    const h16* uir = wih1 + (size_t)j * Hn;
    const h16* uiz = uir + (size_t)Hn * Hn;
    const h16* uin = uiz + (size_t)Hn * Hn;
    const h16* whr = whh1 + (size_t)j * Hn;
    const h16* whz = whr + (size_t)Hn * Hn;
    const h16* whn = whz + (size_t)Hn * Hn;
    const h16* xb = xs + b * PW;
    const h16* hb = hs + b * PW;
    float air = 0.f, aiz = 0.f, ain = 0.f, ahr = 0.f, ahz = 0.f, ahn = 0.f;
#pragma unroll 4
    for (int t = 0; t < 64; ++t) {
      int k = 4 * p + 16 * t;
      h16x4 x4 = *(const h16x4*)(xb + k);
      h16x4 h4 = *(const h16x4*)(hb + k);
      h16x4 a4 = *(const h16x4*)(uir + k);
      h16x4 c4 = *(const h16x4*)(uiz + k);
      h16x4 d4 = *(const h16x4*)(uin + k);
      h16x4 e4 = *(const h16x4*)(whr + k);
      h16x4 f4 = *(const h16x4*)(whz + k);
      h16x4 g4 = *(const h16x4*)(whn + k);
#pragma unroll
      for (int q = 0; q < 4; ++q) {
        float xf = (float)x4[q], hf = (float)h4[q];
        air = fmaf(xf, (float)a4[q], air);
        aiz = fmaf(xf, (float)c4[q], aiz);
        ain = fmaf(xf, (float)d4[q], ain);
        ahr = fmaf(hf, (float)e4[q], ahr);
        ahz = fmaf(hf, (float)f4[q], ahz);
        ahn = fmaf(hf, (float)g4[q], ahn);
      }
    }
    air += __shfl_xor(air, 1, 64); air += __shfl_xor(air, 2, 64);
    aiz += __shfl_xor(aiz, 1, 64); aiz += __shfl_xor(aiz, 2, 64);
    ain += __shfl_xor(ain, 1, 64); ain += __shfl_xor(ain, 2, 64);
    ahr += __shfl_xor(ahr, 1, 64); ahr += __shfl_xor(ahr, 2, 64);
    ahz += __shfl_xor(ahz, 1, 64); ahz += __shfl_xor(ahz, 2, 64);
    ahn += __shfl_xor(ahn, 1, 64); ahn += __shfl_xor(ahn, 2, 64);
    if (p == 0) {
      float ir = air + bih1[j], iz = aiz + bih1[Hn + j], inn = ain + bih1[2 * Hn + j];
      float hr = ahr + bhh1[j], hz = ahz + bhh1[Hn + j], hn = ahn + bhh1[2 * Hn + j];
      float r = 1.f / (1.f + expf(-(ir + hr)));
      float z = 1.f / (1.f + expf(-(iz + hz)));
      float n = tanhf(inn + r * hn);
      float hp = h1p32[b * Hn + j];
      float out = (1.f - z) * n + z * hp;
      h1o32[b * Hn + j] = out;
      h1o16[b * Hn + j] = (h16)out;     // -> H1A[s-1], feeds head GEMM + next step's dots
    }
  }
}

extern "C" void kernel_launch(void* const* d_in, const int* in_sizes, int n_in,
                              void* d_out, int out_size, void* d_ws, size_t ws_size,
                              hipStream_t stream) {
  const float* hidden = (const float*)d_in[0];
  const int*   trg    = (const int*)d_in[1];
  const float* emb    = (const float*)d_in[2];
  const float* w_ih0  = (const float*)d_in[3];
  const float* w_hh0  = (const float*)d_in[4];
  const float* b_ih0  = (const float*)d_in[5];
  const float* b_hh0  = (const float*)d_in[6];
  const float* w_ih1  = (const float*)d_in[7];
  const float* w_hh1  = (const float*)d_in[8];
  const float* b_ih1  = (const float*)d_in[9];
  const float* b_hh1  = (const float*)d_in[10];
  const float* w1     = (const float*)d_in[11];
  const float* b1     = (const float*)d_in[12];
  const float* w2     = (const float*)d_in[13];
  const float* b2     = (const float*)d_in[14];
  const float* b_gen  = (const float*)d_in[15];

  // workspace layout (~90 MB)
  char* ws = (char*)d_ws;
  size_t off = 0;
  float* GI0    = (float*)(ws + off); off += (size_t)Sn * Bn * H3 * 4;      // 25.2 MB
  h16* Xh       = (h16*)(ws + off);   off += (size_t)Sn * Bn * En * 2;      // 2 MB
  h16* embH     = (h16*)(ws + off);   off += (size_t)Vn * En * 2;           // 32.8 MB
  h16* wih0H    = (h16*)(ws + off);   off += (size_t)H3 * En * 2;           // 3.1 MB
  h16* w1H      = (h16*)(ws + off);   off += (size_t)Hn * Hn * 2;           // 2.1 MB
  h16* w2H      = (h16*)(ws + off);   off += (size_t)En * Hn * 2;           // 1 MB
  h16* whh0H    = (h16*)(ws + off);   off += (size_t)H3 * Hn * 2;           // 6.3 MB
  h16* wih1H    = (h16*)(ws + off);   off += (size_t)H3 * Hn * 2;           // 6.3 MB
  h16* whh1H    = (h16*)(ws + off);   off += (size_t)H3 * Hn * 2;           // 6.3 MB
  h16* H1A      = (h16*)(ws + off);   off += (size_t)Sn * Bn * Hn * 2;      // 4.2 MB
  float* h0pp[2]; float* h1pp[2]; h16* h0h[2];
  h0pp[0] = (float*)(ws + off); off += (size_t)Bn * Hn * 4;
  h0pp[1] = (float*)(ws + off); off += (size_t)Bn * Hn * 4;
  h1pp[0] = (float*)(ws + off); off += (size_t)Bn * Hn * 4;
  h1pp[1] = (float*)(ws + off); off += (size_t)Bn * Hn * 4;
  h0h[0]  = (h16*)(ws + off);   off += (size_t)Bn * Hn * 2;
  h0h[1]  = (h16*)(ws + off);   off += (size_t)Bn * Hn * 2;
  h16* hinit16 = (h16*)(ws + off); off += (size_t)2 * Bn * Hn * 2;
  // Tb/Ub alias the (dead-after-recurrence) GI0 region
  h16* Tb = (h16*)GI0;                               // 4 MB
  h16* Ub = (h16*)((char*)GI0 + (8u << 20));         // 2 MB

  // fp16 copies of all GEMM / recurrence operands
  cvt_f16_k<<<16000, 256, 0, stream>>>(emb,   embH,  Vn * En / 4);
  cvt_f16_k<<<1536,  256, 0, stream>>>(w_ih0, wih0H, H3 * En / 4);
  cvt_f16_k<<<1024,  256, 0, stream>>>(w1,    w1H,   Hn * Hn / 4);
  cvt_f16_k<<<512,   256, 0, stream>>>(w2,    w2H,   En * Hn / 4);
  cvt_f16_k<<<3072,  256, 0, stream>>>(w_hh0, whh0H, H3 * Hn / 4);
  cvt_f16_k<<<3072,  256, 0, stream>>>(w_ih1, wih1H, H3 * Hn / 4);
  cvt_f16_k<<<3072,  256, 0, stream>>>(w_hh1, whh1H, H3 * Hn / 4);
  cvt_f16_k<<<32,    256, 0, stream>>>(hidden, hinit16, 2 * Bn * Hn / 4);
  embed_k<<<Sn * Bn, 128, 0, stream>>>(trg, emb, Xh);

  // GI0 = X @ w_ih0^T + b_ih0 (hoisted out of the recurrence)
  gemm_bt<0, false, true><<<384, 256, 0, stream>>>(Xh, wih0H, b_ih0, GI0, Sn * Bn, H3, En);

  // sequential recurrence: 129 launches, layer0[s] pipelined with layer1[s-1]
  const int LDSZ = 2 * 16 * 1032 * 2;   // 66048 B -> 2 blocks/CU
  hipFuncSetAttribute(reinterpret_cast<const void*>(gru_step),
                      hipFuncAttributeMaxDynamicSharedMemorySize, LDSZ);
  for (int s = 0; s <= Sn; ++s) {
    const float* h0p32 = (s == 0) ? hidden : h0pp[(s + 1) & 1];
    float*       h0o32 = h0pp[s & 1];
    const h16*   h0p16 = (s == 0) ? hinit16 : h0h[(s + 1) & 1];
    h16*         h0o16 = h0h[s & 1];
    const float* h1p32 = (s <= 1) ? (hidden + Bn * Hn) : h1pp[s & 1];
    float*       h1o32 = h1pp[(s + 1) & 1];
    const h16*   h1p16 = (s <= 1) ? (hinit16 + Bn * Hn) : (H1A + (size_t)(s - 2) * Bn * Hn);
    h16*         h1o16 = H1A + (size_t)((s >= 1) ? (s - 1) : 0) * Bn * Hn;
    gru_step<<<512, 256, LDSZ, stream>>>(s, GI0, h0p32, h0o32, h0p16, h0o16,
                                         h1p32, h1o32, h1p16, h1o16,
                                         whh0H, b_hh0, wih1H, b_ih1, whh1H, b_hh1);
  }

  // output head, batched over all 2048 rows
  gemm_bt<1, true,  true><<<128,  256, 0, stream>>>(H1A, w1H, b1, Tb, Sn * Bn, Hn, Hn);
  gemm_bt<1, false, true><<<64,   256, 0, stream>>>(Tb, w2H, b2, Ub, Sn * Bn, En, Hn);
  gemm_bt<2, false, true><<<4000, 256, 0, stream>>>(Ub, embH, b_gen, (float*)d_out, Sn * Bn, Vn, En);
}